// Round 11
// baseline (196.281 us; speedup 1.0000x reference)
//
#include <hip/hip_runtime.h>
#include <hip/hip_bf16.h>

#define M 8192
#define N 8192
#define K 512
#define BM 128
#define BN 128
#define BK 64
#define NTS 8  // K-steps (K/BK)

typedef __attribute__((ext_vector_type(8))) short bf16x8;
typedef __attribute__((ext_vector_type(4))) float f32x4;
typedef __attribute__((ext_vector_type(8))) unsigned short us8;

// Raw barrier: wait only LDS ops (ds_writes/reads visible), leave VMEM
// (global loads AND C-stores) in flight across the barrier.
#define BARRIER_LGKM()                                 \
  do {                                                 \
    asm volatile("s_waitcnt lgkmcnt(0)" ::: "memory"); \
    __builtin_amdgcn_s_barrier();                      \
    asm volatile("" ::: "memory");                     \
  } while (0)

__device__ inline us8 cvt8(f32x4 lo, f32x4 hi) {
  us8 o;
#pragma unroll
  for (int i = 0; i < 4; ++i) {
    __hip_bfloat16 b = __float2bfloat16(lo[i]);
    o[i] = *(unsigned short*)&b;
  }
#pragma unroll
  for (int i = 0; i < 4; ++i) {
    __hip_bfloat16 b = __float2bfloat16(hi[i]);
    o[4 + i] = *(unsigned short*)&b;
  }
  return o;
}

// Fully fused cosine-similarity GEMM: f32 inputs -> inline bf16 cast + LDS
// stage (reg-staged), norms accumulated from exact f32 during staging,
// MFMA K-loop, epilogue multiplies by inverse-norm product.
// 4096 blocks x 512 thr (8 waves, wave tile 64x32), 2 blocks/CU, BK=64:
// 16 MFMA per wave per barrier, 8 lgkm-only barriers total in the K-loop.
// LDS granule swizzle (m201 form): 16B slot ^= (row&7) on write and read
// -> conflict-free ds_read_b128 fragment loads.
__global__ __launch_bounds__(512, 4) void fused_kernel(const float* __restrict__ Af,
                                                       const float* __restrict__ Bf,
                                                       float* __restrict__ C) {
  __shared__ __align__(16) unsigned short As[2][BM * BK];  // 2 x 16 KB
  __shared__ __align__(16) unsigned short Bs[2][BN * BK];  // 2 x 16 KB
  __shared__ float w1s[BM], w2s[BN];

  const int tid = threadIdx.x;
  const int wave = tid >> 6;
  const int lane = tid & 63;
  const int wM = wave >> 2;  // 0..1 : 64-row half
  const int wN = wave & 3;   // 0..3 : 32-col quarter
  const int fr = lane & 15;
  const int fq = lane >> 4;

  // Two-level XCD swizzle: xcd owns col-panels [xcd*8, xcd*8+8).
  const int xcd = blockIdx.x & 7;
  const int idx = blockIdx.x >> 3;              // 0..511
  const int bRow = (idx >> 3) * BM;             // 64 row-panels
  const int bCol = (xcd * 8 + (idx & 7)) * BN;  // 64 col-panels

  // Staging mapping: row = tid>>2 (0..127), 4 threads/row, each owns 16
  // consecutive floats (64B) = two 16B bf16 granules g0,g1.
  const int srow = tid >> 2;
  const int sg = tid & 3;
  const int ksw = srow & 7;  // row swizzle key
  // LDS byte offsets of this thread's two granules (slot = g ^ ksw).
  const int offG0 = srow * 128 + ((sg * 2) ^ ksw) * 16;
  const int offG1 = srow * 128 + ((sg * 2 + 1) ^ ksw) * 16;

  f32x4 rA[4], rB[4];
  auto loadR = [&](int t) {
    const float* pa = Af + (size_t)(bRow + srow) * K + t * BK + sg * 16;
#pragma unroll
    for (int i = 0; i < 4; ++i) rA[i] = *(const f32x4*)(pa + i * 4);
    const float* pb = Bf + (size_t)(bCol + srow) * K + t * BK + sg * 16;
#pragma unroll
    for (int i = 0; i < 4; ++i) rB[i] = *(const f32x4*)(pb + i * 4);
  };

  float ssA = 0.f, ssB = 0.f;
  auto stage = [&](int buf) {
    *(us8*)((char*)&As[buf][0] + offG0) = cvt8(rA[0], rA[1]);
    *(us8*)((char*)&As[buf][0] + offG1) = cvt8(rA[2], rA[3]);
    *(us8*)((char*)&Bs[buf][0] + offG0) = cvt8(rB[0], rB[1]);
    *(us8*)((char*)&Bs[buf][0] + offG1) = cvt8(rB[2], rB[3]);
#pragma unroll
    for (int i = 0; i < 4; ++i) {
      ssA += rA[i][0]*rA[i][0] + rA[i][1]*rA[i][1] + rA[i][2]*rA[i][2] + rA[i][3]*rA[i][3];
      ssB += rB[i][0]*rB[i][0] + rB[i][1]*rB[i][1] + rB[i][2]*rB[i][2] + rB[i][3]*rB[i][3];
    }
  };

  // Fragment read: row r, k-half kk -> 16B slot (kk*4+fq) ^ (r&7).
  auto ldfrag = [&](const unsigned short* buf, int r, int kk) -> bf16x8 {
    return *(const bf16x8*)((const char*)buf + r * 128 +
                            (((kk * 4 + fq) ^ (r & 7)) * 16));
  };

  f32x4 acc[4][2] = {};

  // Prologue: stage step 0, issue loads for step 1.
  loadR(0);
  stage(0);
  loadR(1);
  BARRIER_LGKM();

#pragma unroll
  for (int t = 0; t < NTS; ++t) {
    const int cur = t & 1, nxt = cur ^ 1;

    // MFMA first (waits only on its own ds_reads); stage's vmcnt wait then
    // overlaps the MFMA burst; loads reuse the freed stage regs.
#pragma unroll
    for (int kk = 0; kk < 2; ++kk) {
      bf16x8 a[4], b[2];
#pragma unroll
      for (int m = 0; m < 4; ++m) a[m] = ldfrag(&As[cur][0], wM * 64 + m * 16 + fr, kk);
#pragma unroll
      for (int n = 0; n < 2; ++n) b[n] = ldfrag(&Bs[cur][0], wN * 32 + n * 16 + fr, kk);
      __builtin_amdgcn_s_setprio(1);
#pragma unroll
      for (int m = 0; m < 4; ++m)
#pragma unroll
        for (int n = 0; n < 2; ++n)
          acc[m][n] = __builtin_amdgcn_mfma_f32_16x16x32_bf16(a[m], b[n], acc[m][n], 0, 0, 0);
      __builtin_amdgcn_s_setprio(0);
    }

    if (t + 1 < NTS) {
      stage(nxt);                       // consumes R(t+1); implicit vmcnt wait
      if (t + 2 < NTS) loadR(t + 2);    // refill the slot
      BARRIER_LGKM();                   // ds ops drained; VMEM stays in flight
    }
  }

  // Norms: exact f32 sum-of-squares, reduce across the 4 threads of a row.
  ssA += __shfl_xor(ssA, 1, 64);
  ssA += __shfl_xor(ssA, 2, 64);
  ssB += __shfl_xor(ssB, 1, 64);
  ssB += __shfl_xor(ssB, 2, 64);
  if (sg == 0) {
    w1s[srow] = 1.0f / fmaxf(sqrtf(ssA), 1e-4f);
    w2s[srow] = 1.0f / fmaxf(sqrtf(ssB), 1e-4f);
  }
  BARRIER_LGKM();

  // Epilogue. C/D layout: col = lane&15, row = (lane>>4)*4 + reg.
  float i1v[4][4], i2v[2];
#pragma unroll
  for (int m = 0; m < 4; ++m)
#pragma unroll
    for (int r = 0; r < 4; ++r) i1v[m][r] = w1s[wM * 64 + m * 16 + fq * 4 + r];
#pragma unroll
  for (int n = 0; n < 2; ++n) i2v[n] = w2s[wN * 32 + n * 16 + fr];

#pragma unroll
  for (int m = 0; m < 4; ++m) {
    const int row0 = bRow + wM * 64 + m * 16 + fq * 4;
#pragma unroll
    for (int n = 0; n < 2; ++n) {
      const int col = bCol + wN * 32 + n * 16 + fr;
      f32x4 v = acc[m][n];
#pragma unroll
      for (int r = 0; r < 4; ++r)
        C[(size_t)(row0 + r) * N + col] = v[r] * i1v[m][r] * i2v[n];
    }
  }
}

extern "C" void kernel_launch(void* const* d_in, const int* in_sizes, int n_in,
                              void* d_out, int out_size, void* d_ws, size_t ws_size,
                              hipStream_t stream) {
  (void)in_sizes; (void)n_in; (void)out_size; (void)d_ws; (void)ws_size;
  const float* img = (const float*)d_in[0];
  const float* txt = (const float*)d_in[1];
  float* out = (float*)d_out;

  fused_kernel<<<(M / BM) * (N / BN), 512, 0, stream>>>(img, txt, out);
}

// Round 12
// 169.402 us; speedup vs baseline: 1.1587x; 1.1587x over previous
//
#include <hip/hip_runtime.h>
#include <hip/hip_bf16.h>

#define M 8192
#define N 8192
#define K 512
#define BM 128
#define BN 128
#define BK 64
#define NTS 8  // K-steps (K/BK)

typedef __attribute__((ext_vector_type(8))) short bf16x8;
typedef __attribute__((ext_vector_type(4))) float f32x4;
typedef __attribute__((ext_vector_type(8))) unsigned short us8;

// Raw barrier: wait only LDS ops (ds_writes/reads visible), leave VMEM
// (global loads AND C-stores) in flight across the barrier.
#define BARRIER_LGKM()                                 \
  do {                                                 \
    asm volatile("s_waitcnt lgkmcnt(0)" ::: "memory"); \
    __builtin_amdgcn_s_barrier();                      \
    asm volatile("" ::: "memory");                     \
  } while (0)

__device__ inline us8 cvt8(f32x4 lo, f32x4 hi) {
  us8 o;
#pragma unroll
  for (int i = 0; i < 4; ++i) {
    __hip_bfloat16 b = __float2bfloat16(lo[i]);
    o[i] = *(unsigned short*)&b;
  }
#pragma unroll
  for (int i = 0; i < 4; ++i) {
    __hip_bfloat16 b = __float2bfloat16(hi[i]);
    o[4 + i] = *(unsigned short*)&b;
  }
  return o;
}

// Fully fused cosine-similarity GEMM: f32 inputs -> inline bf16 cast + LDS
// stage (reg-staged), norms accumulated from exact f32 during staging,
// MFMA K-loop, epilogue multiplies by inverse-norm product.
// 4096 blocks x 512 thr (8 waves, wave tile 64x32), BK=64: 16 MFMA per wave
// per barrier, 8 lgkm-only barriers in the K-loop.
// __launch_bounds__(512,2): VGPR cap 128 (the (512,4) build capped at 64 and
// spilled ~155MB of scratch per dispatch -- r11 counter evidence). LDS 66.5KB
// already limits occupancy to 2 blocks/CU, so the declared bound loses nothing.
// LDS granule swizzle: 16B slot ^= (row&7) on write and read -> conflict-free
// ds_read_b128 fragment loads.
__global__ __launch_bounds__(512, 2) void fused_kernel(const float* __restrict__ Af,
                                                       const float* __restrict__ Bf,
                                                       float* __restrict__ C) {
  __shared__ __align__(16) unsigned short As[2][BM * BK];  // 2 x 16 KB
  __shared__ __align__(16) unsigned short Bs[2][BN * BK];  // 2 x 16 KB
  __shared__ float w1s[BM], w2s[BN];

  const int tid = threadIdx.x;
  const int wave = tid >> 6;
  const int lane = tid & 63;
  const int wM = wave >> 2;  // 0..1 : 64-row half
  const int wN = wave & 3;   // 0..3 : 32-col quarter
  const int fr = lane & 15;
  const int fq = lane >> 4;

  // Two-level XCD swizzle: xcd owns col-panels [xcd*8, xcd*8+8).
  const int xcd = blockIdx.x & 7;
  const int idx = blockIdx.x >> 3;              // 0..511
  const int bRow = (idx >> 3) * BM;             // 64 row-panels
  const int bCol = (xcd * 8 + (idx & 7)) * BN;  // 64 col-panels

  // Staging mapping: row = tid>>2 (0..127), 4 threads/row, each owns 16
  // consecutive floats (64B) = two 16B bf16 granules g0,g1.
  const int srow = tid >> 2;
  const int sg = tid & 3;
  const int ksw = srow & 7;  // row swizzle key
  const int offG0 = srow * 128 + ((sg * 2) ^ ksw) * 16;
  const int offG1 = srow * 128 + ((sg * 2 + 1) ^ ksw) * 16;

  f32x4 rA[4], rB[4];
  auto loadR = [&](int t) {
    const float* pa = Af + (size_t)(bRow + srow) * K + t * BK + sg * 16;
#pragma unroll
    for (int i = 0; i < 4; ++i) rA[i] = *(const f32x4*)(pa + i * 4);
    const float* pb = Bf + (size_t)(bCol + srow) * K + t * BK + sg * 16;
#pragma unroll
    for (int i = 0; i < 4; ++i) rB[i] = *(const f32x4*)(pb + i * 4);
  };

  float ssA = 0.f, ssB = 0.f;
  auto stage = [&](int buf) {
    *(us8*)((char*)&As[buf][0] + offG0) = cvt8(rA[0], rA[1]);
    *(us8*)((char*)&As[buf][0] + offG1) = cvt8(rA[2], rA[3]);
    *(us8*)((char*)&Bs[buf][0] + offG0) = cvt8(rB[0], rB[1]);
    *(us8*)((char*)&Bs[buf][0] + offG1) = cvt8(rB[2], rB[3]);
#pragma unroll
    for (int i = 0; i < 4; ++i) {
      ssA += rA[i][0]*rA[i][0] + rA[i][1]*rA[i][1] + rA[i][2]*rA[i][2] + rA[i][3]*rA[i][3];
      ssB += rB[i][0]*rB[i][0] + rB[i][1]*rB[i][1] + rB[i][2]*rB[i][2] + rB[i][3]*rB[i][3];
    }
  };

  // Fragment read: row r, k-half kk -> 16B slot (kk*4+fq) ^ (r&7).
  auto ldfrag = [&](const unsigned short* buf, int r, int kk) -> bf16x8 {
    return *(const bf16x8*)((const char*)buf + r * 128 +
                            (((kk * 4 + fq) ^ (r & 7)) * 16));
  };

  f32x4 acc[4][2] = {};

  // Prologue: stage step 0, issue loads for step 1.
  loadR(0);
  stage(0);
  loadR(1);
  BARRIER_LGKM();

#pragma unroll
  for (int t = 0; t < NTS; ++t) {
    const int cur = t & 1, nxt = cur ^ 1;

    // MFMA first (waits only on its own ds_reads); stage's vmcnt wait then
    // overlaps the MFMA burst; loads reuse the freed stage regs.
#pragma unroll
    for (int kk = 0; kk < 2; ++kk) {
      bf16x8 a[4], b[2];
#pragma unroll
      for (int m = 0; m < 4; ++m) a[m] = ldfrag(&As[cur][0], wM * 64 + m * 16 + fr, kk);
#pragma unroll
      for (int n = 0; n < 2; ++n) b[n] = ldfrag(&Bs[cur][0], wN * 32 + n * 16 + fr, kk);
      __builtin_amdgcn_s_setprio(1);
#pragma unroll
      for (int m = 0; m < 4; ++m)
#pragma unroll
        for (int n = 0; n < 2; ++n)
          acc[m][n] = __builtin_amdgcn_mfma_f32_16x16x32_bf16(a[m], b[n], acc[m][n], 0, 0, 0);
      __builtin_amdgcn_s_setprio(0);
    }

    if (t + 1 < NTS) {
      stage(nxt);                       // consumes R(t+1); implicit vmcnt wait
      if (t + 2 < NTS) loadR(t + 2);    // refill the slot
      BARRIER_LGKM();                   // ds ops drained; VMEM stays in flight
    }
  }

  // Norms: exact f32 sum-of-squares, reduce across the 4 threads of a row.
  ssA += __shfl_xor(ssA, 1, 64);
  ssA += __shfl_xor(ssA, 2, 64);
  ssB += __shfl_xor(ssB, 1, 64);
  ssB += __shfl_xor(ssB, 2, 64);
  if (sg == 0) {
    w1s[srow] = 1.0f / fmaxf(sqrtf(ssA), 1e-4f);
    w2s[srow] = 1.0f / fmaxf(sqrtf(ssB), 1e-4f);
  }
  BARRIER_LGKM();

  // Epilogue. C/D layout: col = lane&15, row = (lane>>4)*4 + reg.
  float i1v[4][4], i2v[2];
#pragma unroll
  for (int m = 0; m < 4; ++m)
#pragma unroll
    for (int r = 0; r < 4; ++r) i1v[m][r] = w1s[wM * 64 + m * 16 + fq * 4 + r];
#pragma unroll
  for (int n = 0; n < 2; ++n) i2v[n] = w2s[wN * 32 + n * 16 + fr];

#pragma unroll
  for (int m = 0; m < 4; ++m) {
    const int row0 = bRow + wM * 64 + m * 16 + fq * 4;
#pragma unroll
    for (int n = 0; n < 2; ++n) {
      const int col = bCol + wN * 32 + n * 16 + fr;
      f32x4 v = acc[m][n];
#pragma unroll
      for (int r = 0; r < 4; ++r)
        C[(size_t)(row0 + r) * N + col] = v[r] * i1v[m][r] * i2v[n];
    }
  }
}

extern "C" void kernel_launch(void* const* d_in, const int* in_sizes, int n_in,
                              void* d_out, int out_size, void* d_ws, size_t ws_size,
                              hipStream_t stream) {
  (void)in_sizes; (void)n_in; (void)out_size; (void)d_ws; (void)ws_size;
  const float* img = (const float*)d_in[0];
  const float* txt = (const float*)d_in[1];
  float* out = (float*)d_out;

  fused_kernel<<<(M / BM) * (N / BN), 512, 0, stream>>>(img, txt, out);
}

// Round 13
// 107.488 us; speedup vs baseline: 1.8261x; 1.5760x over previous
//
#include <hip/hip_runtime.h>
#include <hip/hip_bf16.h>

#define M 8192
#define N 8192
#define K 512
#define BM 128
#define BN 128
#define BK 32
#define NT (K / BK)  // 16 K-steps
#define EPAD 132     // epilogue LDS row stride (floats): 528B, 16B-aligned

typedef __attribute__((ext_vector_type(8))) short bf16x8;
typedef __attribute__((ext_vector_type(4))) float f32x4;
typedef __attribute__((ext_vector_type(8))) unsigned short us8;

__device__ inline void gload_lds16(const void* g, void* l) {
  __builtin_amdgcn_global_load_lds(
      (const __attribute__((address_space(1))) unsigned int*)g,
      (__attribute__((address_space(3))) unsigned int*)l, 16, 0, 0);
}

#define BARRIER()                          \
  do {                                     \
    asm volatile("" ::: "memory");         \
    __builtin_amdgcn_s_barrier();          \
    asm volatile("" ::: "memory");         \
  } while (0)

// lgkm-only barrier: LDS ops drained, VMEM (global loads/stores) in flight.
#define BARRIER_LGKM()                                 \
  do {                                                 \
    asm volatile("s_waitcnt lgkmcnt(0)" ::: "memory"); \
    __builtin_amdgcn_s_barrier();                      \
    asm volatile("" ::: "memory");                     \
  } while (0)

// Fused prep: cast f32 rows -> bf16, store INVERSE L2 norm (1/max(norm,1e-4)).
__global__ __launch_bounds__(256) void prep_kernel(const float* __restrict__ img,
                                                   const float* __restrict__ txt,
                                                   unsigned short* __restrict__ Abf,
                                                   unsigned short* __restrict__ Bbf,
                                                   float* __restrict__ w1,
                                                   float* __restrict__ w2) {
  const int half = blockIdx.x >> 11;
  const int lb = blockIdx.x & 2047;
  const float* in = half ? txt : img;
  unsigned short* outb = half ? Bbf : Abf;
  float* norms = half ? w2 : w1;

  const int gw = (lb * 256 + threadIdx.x) >> 6;
  const int lane = threadIdx.x & 63;
  const float4* rp4 = (const float4*)(in + (size_t)gw * K);
  float4 v0 = rp4[lane * 2];
  float4 v1 = rp4[lane * 2 + 1];
  float ss = v0.x * v0.x + v0.y * v0.y + v0.z * v0.z + v0.w * v0.w +
             v1.x * v1.x + v1.y * v1.y + v1.z * v1.z + v1.w * v1.w;
  float f[8] = {v0.x, v0.y, v0.z, v0.w, v1.x, v1.y, v1.z, v1.w};
  us8 o;
#pragma unroll
  for (int i = 0; i < 8; ++i) {
    __hip_bfloat16 b = __float2bfloat16(f[i]);
    o[i] = *(unsigned short*)&b;
  }
  *(us8*)(outb + (size_t)gw * K + lane * 8) = o;
#pragma unroll
  for (int off = 32; off > 0; off >>= 1) ss += __shfl_down(ss, off, 64);
  if (lane == 0) norms[gw] = 1.0f / fmaxf(sqrtf(ss), 1e-4f);
}

// 128x128 bf16 GEMM (r9 K-loop, proven) + FULL-LINE epilogue:
// output tile staged through LDS and stored as f32x4/lane (512B contiguous
// per wave-row) so every 128B L2 line is covered by one instruction ->
// no read-modify-write fetch of C lines (r1/r3 counter evidence).
__global__ __launch_bounds__(256, 4) void gemm_kernel(const unsigned short* __restrict__ A,
                                                      const unsigned short* __restrict__ B,
                                                      const float* __restrict__ iw1,
                                                      const float* __restrict__ iw2,
                                                      float* __restrict__ C) {
  // 40 KB shared pool: K-loop As[2]/Bs[3] overlaid with epilogue tile (33.8 KB)
  __shared__ __align__(16) char smem[(2 * BM * BK + 3 * BN * BK) * 2];
  auto AsP = [&](int buf) { return (unsigned short*)(smem + buf * BM * BK * 2); };
  auto BsP = [&](int buf) { return (unsigned short*)(smem + 2 * BM * BK * 2 + buf * BN * BK * 2); };
  float* eps = (float*)smem;  // epilogue: 64 rows x EPAD floats

  const int tid = threadIdx.x;
  const int wave = tid >> 6;  // 0..3
  const int lane = tid & 63;
  const int wr = wave >> 1;  // 0..1 : M strip of 64
  const int wc = wave & 1;   // 0..1 : N strip of 64
  const int fr = lane & 15;
  const int fq = lane >> 4;

  // Two-level swizzle: xcd owns col-panels [xcd*8, xcd*8+8).
  const int xcd = blockIdx.x & 7;
  const int idx = blockIdx.x >> 3;              // 0..511
  const int bRow = (idx >> 3) * BM;             // 64 row-panels of 128
  const int bCol = (xcd * 8 + (idx & 7)) * BN;  // 64 col-panels of 128

  // Staging: 16 rows x 64B per wave per call; source granule pre-swizzled
  // so LDS slot jl holds global granule jl ^ ((row>>1)&3)  (rule #21).
  const int srow = lane >> 2;                               // 0..15
  const int scol = (((lane & 3) ^ ((srow >> 1) & 3)) * 8);  // bf16 offset

  auto stageA = [&](int buf, int kt) {
#pragma unroll
    for (int c = 0; c < 2; ++c)
      gload_lds16(A + (size_t)(bRow + c * 64 + wave * 16 + srow) * K + kt * BK + scol,
                  (char*)AsP(buf) + (c * 64 + wave * 16) * 64);
  };
  auto stageB = [&](int buf, int kt) {
#pragma unroll
    for (int c = 0; c < 2; ++c)
      gload_lds16(B + (size_t)(bCol + c * 64 + wave * 16 + srow) * K + kt * BK + scol,
                  (char*)BsP(buf) + (c * 64 + wave * 16) * 64);
  };
  auto ldA = [&](int buf, int r) -> bf16x8 {
    return *(const bf16x8*)((const char*)AsP(buf) + r * 64 + ((fq ^ ((r >> 1) & 3)) * 16));
  };
  auto ldB = [&](int buf, int r) -> bf16x8 {
    return *(const bf16x8*)((const char*)BsP(buf) + r * 64 + ((fq ^ ((r >> 1) & 3)) * 16));
  };

  f32x4 acc[4][4] = {};

  // Prologue: A(0) x2, B(0) x2, B(1) x2 -> need A0,B0 landed, B1 in flight.
  stageA(0, 0);
  stageB(0, 0);
  stageB(1, 1);
  asm volatile("s_waitcnt vmcnt(2)" ::: "memory");
  BARRIER();

#pragma unroll
  for (int t = 0; t < NT; ++t) {
    const int cur = t & 1, nxt = cur ^ 1;
    const int bc = t % 3, b2 = (t + 2) % 3;

    if (t + 1 < NT) stageA(nxt, t + 1);  // 2 gloads
    if (t + 2 < NT) stageB(b2, t + 2);   // 2 gloads

    bf16x8 a[4], b[4];
#pragma unroll
    for (int m = 0; m < 4; ++m) a[m] = ldA(cur, wr * 64 + m * 16 + fr);
#pragma unroll
    for (int n = 0; n < 4; ++n) b[n] = ldB(bc, wc * 64 + n * 16 + fr);

    __builtin_amdgcn_s_setprio(1);
#pragma unroll
    for (int m = 0; m < 4; ++m)
#pragma unroll
      for (int n = 0; n < 4; ++n)
        acc[m][n] = __builtin_amdgcn_mfma_f32_16x16x32_bf16(a[m], b[n], acc[m][n], 0, 0, 0);
    __builtin_amdgcn_s_setprio(0);

    if (t < NT - 2) {
      asm volatile("s_waitcnt vmcnt(2)" ::: "memory");
    } else if (t == NT - 2) {
      asm volatile("s_waitcnt vmcnt(0)" ::: "memory");
    }
    BARRIER();
  }

  // Norm scales. C/D layout: col = lane&15, row = (lane>>4)*4 + reg.
  float i1v[4][4], i2v[4];
#pragma unroll
  for (int m = 0; m < 4; ++m)
#pragma unroll
    for (int r = 0; r < 4; ++r) i1v[m][r] = iw1[bRow + wr * 64 + m * 16 + fq * 4 + r];
#pragma unroll
  for (int n = 0; n < 4; ++n) i2v[n] = iw2[bCol + wc * 64 + n * 16 + fr];

  // Full-line epilogue: two 64-row halves through LDS.
  const int erow = tid >> 5;        // 0..7 (row-within-pass)
  const int ecol = (tid & 31) * 4;  // f32 col (covers 0..127)
#pragma unroll
  for (int h = 0; h < 2; ++h) {
    BARRIER_LGKM();  // h=0: K-loop ds ops done; h=1: prior readout reads done
#pragma unroll
    for (int dm = 0; dm < 2; ++dm) {
      const int m = 2 * h + dm;
#pragma unroll
      for (int n = 0; n < 4; ++n) {
        f32x4 v = acc[m][n];
        const int lc = wc * 64 + n * 16 + fr;
#pragma unroll
        for (int r = 0; r < 4; ++r) {
          const int lr = wr * 32 + dm * 16 + fq * 4 + r;
          eps[lr * EPAD + lc] = v[r] * i1v[m][r] * i2v[n];
        }
      }
    }
    BARRIER_LGKM();
#pragma unroll
    for (int p = 0; p < 8; ++p) {
      const int lr = p * 8 + erow;  // 0..63
      f32x4 v = *(const f32x4*)&eps[lr * EPAD + ecol];
      const int gRow = bRow + (lr >> 5) * 64 + (2 * h + ((lr >> 4) & 1)) * 16 + (lr & 15);
      *(f32x4*)&C[(size_t)gRow * N + bCol + ecol] = v;
    }
  }
}

extern "C" void kernel_launch(void* const* d_in, const int* in_sizes, int n_in,
                              void* d_out, int out_size, void* d_ws, size_t ws_size,
                              hipStream_t stream) {
  (void)in_sizes; (void)n_in; (void)out_size; (void)ws_size;
  const float* img = (const float*)d_in[0];
  const float* txt = (const float*)d_in[1];
  float* out = (float*)d_out;

  unsigned short* Abf = (unsigned short*)d_ws;
  unsigned short* Bbf = Abf + (size_t)M * K;
  float* w1 = (float*)(Bbf + (size_t)N * K);
  float* w2 = w1 + M;

  prep_kernel<<<4096, 256, 0, stream>>>(img, txt, Abf, Bbf, w1, w2);
  gemm_kernel<<<(M / BM) * (N / BN), 256, 0, stream>>>(Abf, Bbf, w1, w2, out);
}